// Round 4
// baseline (300.996 us; speedup 1.0000x reference)
//
#include <hip/hip_runtime.h>

// ---------------- problem constants ----------------
#define NB    1024
#define NN    19
#define NF    8
#define CCH   152         // NN*NF
#define TLEN  512
#define TP    128
#define GO    16
#define KFLAT 38912       // NN*TP*GO
#define HID   128
#define NCLS  2
#define NROWS (NB*TP)     // 131072 GEMM rows (b,t)
#define KC    152         // h channels (j,f)
#define KP    160         // padded K (5 * 32)
#define NOUT  304         // NN*GO Kronecker output cols
#define M2LDSW 168        // LDS row stride for M (bank-conflict-free)

// FC1 GEMM split-K config
#define KTILE 512
#define NKT   (KFLAT / KTILE)   // 76

typedef float  f32x4  __attribute__((ext_vector_type(4)));
typedef __bf16 bf16x8 __attribute__((ext_vector_type(8)));
typedef __bf16 bf16x4 __attribute__((ext_vector_type(4)));
typedef unsigned short u16x8 __attribute__((ext_vector_type(8)));

// ---------------------------------------------------------------------------
// Kernel P1: softmax(adj) rows + fused BN affine (single block, trivial)
// ---------------------------------------------------------------------------
__global__ __launch_bounds__(256) void prep_small(
    const float* __restrict__ adj,
    const float* __restrict__ bn_gamma, const float* __restrict__ bn_beta,
    const float* __restrict__ bn_mean,  const float* __restrict__ bn_var,
    const float* __restrict__ conv_b,
    float* __restrict__ A_g, float* __restrict__ bnS, float* __restrict__ bnB)
{
    const int tid = threadIdx.x;
    if (tid < NN) {
        float v[NN];
        float m = -1e30f;
        #pragma unroll
        for (int j = 0; j < NN; ++j) { v[j] = adj[tid * NN + j]; m = fmaxf(m, v[j]); }
        float s = 0.f;
        #pragma unroll
        for (int j = 0; j < NN; ++j) { v[j] = expf(v[j] - m); s += v[j]; }
        float rc = 1.f / s;
        #pragma unroll
        for (int j = 0; j < NN; ++j) A_g[tid * NN + j] = v[j] * rc;
    }
    if (tid >= 64 && tid < 64 + CCH) {
        int c = tid - 64;
        float inv = bn_gamma[c] * rsqrtf(bn_var[c] + 1e-5f);
        bnS[c] = inv;
        bnB[c] = conv_b[c] * inv + bn_beta[c] - bn_mean[c] * inv;
    }
}

// ---------------------------------------------------------------------------
// Kernel P2: Kronecker matrix M[(n,o)][(j,f)] = A[n,j]*gcn_w[o,f], bf16,
//   layout [NOUT][KP] (k padded 152..159 with zeros).
// ---------------------------------------------------------------------------
__global__ __launch_bounds__(256) void prep_m2(
    const float* __restrict__ A_g, const float* __restrict__ gcn_w,
    __bf16* __restrict__ m2)
{
    int i = blockIdx.x * 256 + threadIdx.x;
    if (i >= NOUT * KP) return;
    int col = i / KP, k = i - col * KP;
    int n = col >> 4, o = col & 15;
    float v = 0.f;
    if (k < KC) {
        int j = k >> 3, f = k & 7;
        v = A_g[n * NN + j] * gcn_w[o * NF + f];
    }
    m2[i] = (__bf16)v;
}

// ---------------------------------------------------------------------------
// Kernel A: conv(k5 depthwise)+bias+BN+ReLU+maxpool4 -> H[(b,t)][c] bf16.
//   block = (b,n) so all weights are wave-uniform (scalar loads);
//   thread = tp. No LDS, no barriers.
// ---------------------------------------------------------------------------
__global__ __launch_bounds__(128) void conv_pool(
    const float* __restrict__ x,       // [NB][NN][TLEN]
    const float* __restrict__ conv_w,  // [CCH][5]
    const float* __restrict__ bnS, const float* __restrict__ bnB,
    __bf16* __restrict__ H)            // [NROWS][KP]
{
    const int bid = blockIdx.x;
    const int b = bid / NN, n = bid - b * NN;   // scalar
    const int tp = threadIdx.x;                  // 0..127

    const float* xr = x + ((size_t)b * NN + n) * TLEN;
    float xv[8];
    #pragma unroll
    for (int e = 0; e < 8; ++e) {
        int tg = 4 * tp - 2 + e;
        xv[e] = (tg >= 0 && tg < TLEN) ? xr[tg] : 0.f;
    }
    const float* cw = conv_w + n * (NF * 5);
    const float* Sp = bnS + n * NF;
    const float* Bp = bnB + n * NF;

    union { __bf16 h[8]; u16x8 v; } hv;
    #pragma unroll
    for (int f = 0; f < NF; ++f) {
        float w0 = cw[f*5+0], w1 = cw[f*5+1], w2 = cw[f*5+2], w3 = cw[f*5+3], w4 = cw[f*5+4];
        float s = Sp[f], bb = Bp[f];
        float m = -1e30f;
        #pragma unroll
        for (int p = 0; p < 4; ++p) {
            float a = xv[p]*w0 + xv[p+1]*w1 + xv[p+2]*w2 + xv[p+3]*w3 + xv[p+4]*w4;
            m = fmaxf(m, a * s + bb);
        }
        hv.h[f] = (__bf16)fmaxf(m, 0.f);
    }
    size_t row = (size_t)b * TP + tp;
    *(u16x8*)(H + row * KP + n * NF) = hv.v;
    if (n == NN - 1) {                    // zero the K padding (cols 152..159)
        u16x8 z = {0,0,0,0,0,0,0,0};
        *(u16x8*)(H + row * KP + KC) = z;
    }
}

// ---------------------------------------------------------------------------
// Kernel B: MFMA Kronecker contraction g = relu(H @ M^T + gcn_b).
//   M (NOUT x KP) staged once in LDS (stride 168 elems: conflict-free b128).
//   grid 256 blocks x 8 waves x 4 tiles x 16 rows = 131072 rows.
// ---------------------------------------------------------------------------
__global__ __launch_bounds__(512) void mix_gcn(
    const __bf16* __restrict__ H,      // [NROWS][KP]
    const __bf16* __restrict__ m2,     // [NOUT][KP]
    const float* __restrict__ gcn_b,   // [GO]
    __bf16* __restrict__ g_out)        // [NB][KFLAT]
{
    __shared__ __align__(16) __bf16 m2s[NOUT][M2LDSW];
    __shared__ float gbs[GO];

    const int tid = threadIdx.x;
    for (int i = tid; i < NOUT * (KP / 8); i += 512) {   // 6080 16B chunks
        int r = i / 20, c8 = i - r * 20;
        *(u16x8*)&m2s[r][c8 * 8] = *(const u16x8*)(m2 + (size_t)r * KP + c8 * 8);
    }
    if (tid < GO) gbs[tid] = gcn_b[tid];
    __syncthreads();

    const int lane = tid & 63, w = tid >> 6;
    const int arow = lane & 15, aoct = (lane >> 4) * 8;
    const float gb = gbs[lane & 15];

    for (int i = 0; i < 4; ++i) {
        const int tile = blockIdx.x * 32 + w * 4 + i;
        const int R0 = tile * 16;

        const __bf16* hp = H + (size_t)(R0 + arow) * KP + aoct;
        bf16x8 af[5];
        #pragma unroll
        for (int ks = 0; ks < 5; ++ks) af[ks] = *(const bf16x8*)(hp + ks * 32);

        f32x4 acc[NN];
        #pragma unroll
        for (int ct = 0; ct < NN; ++ct) acc[ct] = (f32x4){0.f, 0.f, 0.f, 0.f};

        #pragma unroll
        for (int ks = 0; ks < 5; ++ks) {
            #pragma unroll
            for (int ct = 0; ct < NN; ++ct) {
                bf16x8 bfr = *(const bf16x8*)&m2s[ct * 16 + arow][ks * 32 + aoct];
                acc[ct] = __builtin_amdgcn_mfma_f32_16x16x32_bf16(af[ks], bfr, acc[ct], 0, 0, 0);
            }
        }

        // epilogue: C/D layout col = lane&15 (=o), row = (lane>>4)*4 + r
        const int rbase = R0 + (lane >> 4) * 4;
        const int o = lane & 15;
        #pragma unroll
        for (int ct = 0; ct < NN; ++ct) {
            #pragma unroll
            for (int r = 0; r < 4; ++r) {
                int row = rbase + r;               // = b*128 + t (16 | 128: no b-cross)
                int b = row >> 7, t = row & 127;
                float v = fmaxf(acc[ct][r] + gb, 0.f);
                g_out[(size_t)b * KFLAT + ct * (TP * GO) + t * GO + o] = (__bf16)v;
            }
        }
    }
}

// ---------------------------------------------------------------------------
// Kernel 2: w1 fp32 -> bf16
// ---------------------------------------------------------------------------
__global__ __launch_bounds__(256) void w1_to_bf16(
    const float* __restrict__ w1, __bf16* __restrict__ o)
{
    const int n4 = (HID * KFLAT) >> 2;
    for (int i = blockIdx.x * 256 + threadIdx.x; i < n4; i += gridDim.x * 256) {
        float4 v = ((const float4*)w1)[i];
        bf16x4 r;
        r[0] = (__bf16)v.x; r[1] = (__bf16)v.y; r[2] = (__bf16)v.z; r[3] = (__bf16)v.w;
        ((bf16x4*)o)[i] = r;
    }
}

// ---------------------------------------------------------------------------
// Kernel 3: split-K bf16 MFMA GEMM: C[b,j] += sum_k g[b,k]*w1[j,k]
// ---------------------------------------------------------------------------
__global__ __launch_bounds__(256) void gemm_fc1(
    const __bf16* __restrict__ gmat,   // [NB][KFLAT]
    const __bf16* __restrict__ wmat,   // [HID][KFLAT]
    float* __restrict__ partial)       // [NKT][NB][HID]
{
    __shared__ __align__(16) __bf16 At[128][40];
    __shared__ __align__(16) __bf16 Bt[128][40];

    const int tid = threadIdx.x;
    const int b0 = blockIdx.x * 128;
    const int k0 = blockIdx.y * KTILE;

    const int lane = tid & 63;
    const int w = tid >> 6;
    const int wm = (w >> 1) * 64;
    const int wn = (w & 1) * 64;

    const int srow = tid >> 2;
    const int soct = tid & 3;

    f32x4 acc[4][4];
    #pragma unroll
    for (int m = 0; m < 4; ++m)
        #pragma unroll
        for (int n = 0; n < 4; ++n) acc[m][n] = (f32x4){0.f, 0.f, 0.f, 0.f};

    const int arow = lane & 15;
    const int aoct = (lane >> 4) * 8;

    for (int ks = 0; ks < KTILE / 32; ++ks) {
        const int gk = k0 + ks * 32 + soct * 8;
        *(u16x8*)&At[srow     ][soct * 8] = *(const u16x8*)(gmat + (size_t)(b0 + srow     ) * KFLAT + gk);
        *(u16x8*)&At[srow + 64][soct * 8] = *(const u16x8*)(gmat + (size_t)(b0 + srow + 64) * KFLAT + gk);
        *(u16x8*)&Bt[srow     ][soct * 8] = *(const u16x8*)(wmat + (size_t)(srow     ) * KFLAT + gk);
        *(u16x8*)&Bt[srow + 64][soct * 8] = *(const u16x8*)(wmat + (size_t)(srow + 64) * KFLAT + gk);
        __syncthreads();

        bf16x8 af[4], bfr[4];
        #pragma unroll
        for (int m = 0; m < 4; ++m) af[m]  = *(const bf16x8*)&At[wm + m * 16 + arow][aoct];
        #pragma unroll
        for (int n = 0; n < 4; ++n) bfr[n] = *(const bf16x8*)&Bt[wn + n * 16 + arow][aoct];
        #pragma unroll
        for (int m = 0; m < 4; ++m)
            #pragma unroll
            for (int n = 0; n < 4; ++n)
                acc[m][n] = __builtin_amdgcn_mfma_f32_16x16x32_bf16(af[m], bfr[n], acc[m][n], 0, 0, 0);
        __syncthreads();
    }

    float* pout = partial + (size_t)blockIdx.y * (NB * HID);
    #pragma unroll
    for (int m = 0; m < 4; ++m) {
        const int rbase = b0 + wm + m * 16 + (lane >> 4) * 4;
        #pragma unroll
        for (int n = 0; n < 4; ++n) {
            const int col = wn + n * 16 + (lane & 15);
            #pragma unroll
            for (int r = 0; r < 4; ++r)
                pout[(size_t)(rbase + r) * HID + col] = acc[m][n][r];
        }
    }
}

// ---------------------------------------------------------------------------
// Kernel 4: reduce split-K partials + b1 + ReLU, then FC2 (128->2) + b2
// ---------------------------------------------------------------------------
__global__ __launch_bounds__(128) void reduce_fc2(
    const float* __restrict__ partial,  // [NKT][NB][HID]
    const float* __restrict__ b1,
    const float* __restrict__ w2,       // [NCLS][HID]
    const float* __restrict__ b2,
    float* __restrict__ out)            // [NB][NCLS]
{
    __shared__ float red0[128], red1[128];
    const int b = blockIdx.x, j = threadIdx.x;
    float s = b1[j];
    #pragma unroll 4
    for (int p = 0; p < NKT; ++p) s += partial[(size_t)p * (NB * HID) + b * HID + j];
    float h = fmaxf(s, 0.f);
    red0[j] = h * w2[j];
    red1[j] = h * w2[HID + j];
    __syncthreads();
    for (int off = 64; off > 0; off >>= 1) {
        if (j < off) { red0[j] += red0[j + off]; red1[j] += red1[j + off]; }
        __syncthreads();
    }
    if (j == 0) {
        out[b * 2 + 0] = red0[0] + b2[0];
        out[b * 2 + 1] = red1[0] + b2[1];
    }
}

// ---------------------------------------------------------------------------
extern "C" void kernel_launch(void* const* d_in, const int* in_sizes, int n_in,
                              void* d_out, int out_size, void* d_ws, size_t ws_size,
                              hipStream_t stream) {
    const float* x        = (const float*)d_in[0];
    const float* conv_w   = (const float*)d_in[1];
    const float* conv_b   = (const float*)d_in[2];
    const float* bn_gamma = (const float*)d_in[3];
    const float* bn_beta  = (const float*)d_in[4];
    const float* bn_mean  = (const float*)d_in[5];
    const float* bn_var   = (const float*)d_in[6];
    const float* adj      = (const float*)d_in[7];
    const float* gcn_w    = (const float*)d_in[8];
    const float* gcn_b    = (const float*)d_in[9];
    const float* w1       = (const float*)d_in[10];
    const float* b1       = (const float*)d_in[11];
    const float* w2       = (const float*)d_in[12];
    const float* b2       = (const float*)d_in[13];
    float* out = (float*)d_out;

    // workspace (total 129,499,136 B, lifetime-overlapped):
    //   g     [0,          79,691,776)   written by mix_gcn, read by gemm
    //   aux   [79,691,776, 79,793,152)   A_g/bnS/bnB/m2 — dead after mix_gcn
    //   H     [87,556,096, 129,499,136)  conv_pool -> mix_gcn, then dead
    //   w1b   [79,691,776, 89,653,248)   written AFTER mix_gcn (overlaps aux+H tail)
    //   part  [89,653,248, 129,499,136)  written by gemm AFTER H dead
    char* ws = (char*)d_ws;
    __bf16* gmat = (__bf16*)ws;
    char*   aux  = ws + 79691776;
    float*  A_g  = (float*)aux;
    float*  bnS  = (float*)(aux + 2048);
    float*  bnB  = (float*)(aux + 3072);
    __bf16* m2   = (__bf16*)(aux + 4096);
    __bf16* w1b  = (__bf16*)(ws + 79691776);
    __bf16* Hbuf = (__bf16*)(ws + 87556096);
    float*  part = (float*)(ws + 89653248);

    prep_small<<<dim3(1), dim3(256), 0, stream>>>(
        adj, bn_gamma, bn_beta, bn_mean, bn_var, conv_b, A_g, bnS, bnB);
    prep_m2<<<dim3(190), dim3(256), 0, stream>>>(A_g, gcn_w, m2);
    conv_pool<<<dim3(NB * NN), dim3(128), 0, stream>>>(x, conv_w, bnS, bnB, Hbuf);
    mix_gcn<<<dim3(256), dim3(512), 0, stream>>>(Hbuf, m2, gcn_b, gmat);
    w1_to_bf16<<<dim3(1024), dim3(256), 0, stream>>>(w1, w1b);
    gemm_fc1<<<dim3(8, NKT), dim3(256), 0, stream>>>(gmat, w1b, part);
    reduce_fc2<<<dim3(NB), dim3(128), 0, stream>>>(part, b1, w2, b2, out);
}

// Round 6
// 138.269 us; speedup vs baseline: 2.1769x; 2.1769x over previous
//
#include <hip/hip_runtime.h>

// ---------------- problem constants ----------------
#define NB    1024
#define NN    19
#define NF    8
#define CCH   152         // NN*NF
#define TLEN  512
#define TP    128
#define GO    16
#define KFLAT 38912       // reference flat K (n*2048 + t*16 + o)
#define HID   128
#define NCLS  2
#define NROWS (NB*TP)     // 131072 (b,t) rows
#define KC    152         // conv channels (j,f)
#define KP    160         // padded K for mix (5*32)
#define NOUT  304         // NN*GO
#define COLB  160         // g2 cols per ct-group block
#define GW    320         // g2 padded row width
#define KW    (TP*GW)     // 40960: FC1 K in permuted order
#define M2W   168         // LDS row stride (bank-safe, 16B-aligned)

// FC1 GEMM split-K
#define KTILE 1024
#define NKT   (KW / KTILE)   // 40

typedef float  f32x4  __attribute__((ext_vector_type(4)));
typedef __bf16 bf16x8 __attribute__((ext_vector_type(8)));
typedef __bf16 bf16x4 __attribute__((ext_vector_type(4)));
typedef unsigned short u16x8 __attribute__((ext_vector_type(8)));

// ---------------------------------------------------------------------------
// P1: softmax(adj) + fused BN affine (1 block)
// ---------------------------------------------------------------------------
__global__ __launch_bounds__(256) void prep_small(
    const float* __restrict__ adj,
    const float* __restrict__ bn_gamma, const float* __restrict__ bn_beta,
    const float* __restrict__ bn_mean,  const float* __restrict__ bn_var,
    const float* __restrict__ conv_b,
    float* __restrict__ A_g, float* __restrict__ bnS, float* __restrict__ bnB)
{
    const int tid = threadIdx.x;
    if (tid < NN) {
        float v[NN];
        float m = -1e30f;
        #pragma unroll
        for (int j = 0; j < NN; ++j) { v[j] = adj[tid * NN + j]; m = fmaxf(m, v[j]); }
        float s = 0.f;
        #pragma unroll
        for (int j = 0; j < NN; ++j) { v[j] = expf(v[j] - m); s += v[j]; }
        float rc = 1.f / s;
        #pragma unroll
        for (int j = 0; j < NN; ++j) A_g[tid * NN + j] = v[j] * rc;
    }
    if (tid >= 64 && tid < 64 + CCH) {
        int c = tid - 64;
        float inv = bn_gamma[c] * rsqrtf(bn_var[c] + 1e-5f);
        bnS[c] = inv;
        bnB[c] = conv_b[c] * inv + bn_beta[c] - bn_mean[c] * inv;
    }
}

// ---------------------------------------------------------------------------
// P2: Kronecker matrix m2g[c][k] = A[n,j]*gcn_w[o,f], c=(n*16+o) in [0,320)
//     (rows 304..319 and k 152..159 zero-padded), bf16.
// ---------------------------------------------------------------------------
__global__ __launch_bounds__(256) void prep_m2(
    const float* __restrict__ A_g, const float* __restrict__ gcn_w,
    __bf16* __restrict__ m2g)
{
    int i = blockIdx.x * 256 + threadIdx.x;
    if (i >= GW * KP) return;
    int c = i / KP, k = i - c * KP;
    float v = 0.f;
    if (c < NOUT && k < KC) {
        int n = c >> 4, o = c & 15;
        int j = k >> 3, f = k & 7;
        v = A_g[n * NN + j] * gcn_w[o * NF + f];
    }
    m2g[i] = (__bf16)v;
}

// ---------------------------------------------------------------------------
// A: conv(k5 depthwise)+bias+BN+ReLU+maxpool4 -> H[(b,t)][c] bf16, K padded.
//    block=(b,n): weights wave-uniform; thread=tp. No LDS/barriers.
// ---------------------------------------------------------------------------
__global__ __launch_bounds__(128) void conv_pool(
    const float* __restrict__ x,       // [NB][NN][TLEN]
    const float* __restrict__ conv_w,  // [CCH][5]
    const float* __restrict__ bnS, const float* __restrict__ bnB,
    __bf16* __restrict__ H)            // [NROWS][KP]
{
    const int bid = blockIdx.x;
    const int b = bid / NN, n = bid - b * NN;
    const int tp = threadIdx.x;

    const float* xr = x + ((size_t)b * NN + n) * TLEN;
    float xv[8];
    #pragma unroll
    for (int e = 0; e < 8; ++e) {
        int tg = 4 * tp - 2 + e;
        xv[e] = (tg >= 0 && tg < TLEN) ? xr[tg] : 0.f;
    }
    const float* cw = conv_w + n * (NF * 5);
    const float* Sp = bnS + n * NF;
    const float* Bp = bnB + n * NF;

    union { __bf16 h[8]; u16x8 v; } hv;
    #pragma unroll
    for (int f = 0; f < NF; ++f) {
        float w0 = cw[f*5+0], w1 = cw[f*5+1], w2 = cw[f*5+2], w3 = cw[f*5+3], w4 = cw[f*5+4];
        float s = Sp[f], bb = Bp[f];
        float m = -1e30f;
        #pragma unroll
        for (int p = 0; p < 4; ++p) {
            float a = xv[p]*w0 + xv[p+1]*w1 + xv[p+2]*w2 + xv[p+3]*w3 + xv[p+4]*w4;
            m = fmaxf(m, a * s + bb);
        }
        hv.h[f] = (__bf16)fmaxf(m, 0.f);
    }
    size_t row = (size_t)b * TP + tp;
    *(u16x8*)(H + row * KP + n * NF) = hv.v;
    if (n == NN - 1) {
        u16x8 z = {0,0,0,0,0,0,0,0};
        *(u16x8*)(H + row * KP + KC) = z;
    }
}

// ---------------------------------------------------------------------------
// B: MFMA contraction g2 = relu(H @ m2^T + gcn_b), g2[(b,t)][320].
//    Block = 64 rows x one 160-col ct-group; m2 block in LDS (stride 168,
//    2-way = free); epilogue via wave-private LDS staging -> full-line
//    16B stores (fixes R4's 530 MB HBM inflation).
// ---------------------------------------------------------------------------
__global__ __launch_bounds__(256) void mix_gcn(
    const __bf16* __restrict__ H,      // [NROWS][KP]
    const __bf16* __restrict__ m2g,    // [GW][KP]
    const float* __restrict__ gcn_b,   // [GO]
    __bf16* __restrict__ g2)           // [NROWS][GW]
{
    __shared__ __align__(16) __bf16 m2s[COLB][M2W];   // 53,760 B
    __shared__ __align__(16) __bf16 stg[64][M2W];     // 21,504 B
    __shared__ float gbs[GO];

    const int tid = threadIdx.x;
    const int rg  = blockIdx.x >> 1;      // 64-row group
    const int ctg = blockIdx.x & 1;       // ct half (cols ctg*160..+160)

    for (int i = tid; i < COLB * (KP / 8); i += 256) {  // 3200 16B chunks
        int r = i / 20, c8 = i - r * 20;
        *(u16x8*)&m2s[r][c8 * 8] =
            *(const u16x8*)(m2g + (size_t)(ctg * COLB + r) * KP + c8 * 8);
    }
    if (tid < GO) gbs[tid] = gcn_b[tid];
    __syncthreads();

    const int lane = tid & 63, w = tid >> 6;
    const int arow = lane & 15, aoct = (lane >> 4) * 8;
    const float gb = gbs[lane & 15];
    const int R0 = rg * 64 + w * 16;

    const __bf16* hp = H + (size_t)(R0 + arow) * KP + aoct;
    bf16x8 af[5];
    #pragma unroll
    for (int ks = 0; ks < 5; ++ks) af[ks] = *(const bf16x8*)(hp + ks * 32);

    f32x4 acc[10];
    #pragma unroll
    for (int ct = 0; ct < 10; ++ct) acc[ct] = (f32x4){0.f, 0.f, 0.f, 0.f};

    #pragma unroll
    for (int ks = 0; ks < 5; ++ks)
        #pragma unroll
        for (int ct = 0; ct < 10; ++ct) {
            bf16x8 bfr = *(const bf16x8*)&m2s[ct * 16 + arow][ks * 32 + aoct];
            acc[ct] = __builtin_amdgcn_mfma_f32_16x16x32_bf16(af[ks], bfr, acc[ct], 0, 0, 0);
        }

    // epilogue: acc -> wave-private staging rows [w*16, w*16+16)
    const int lr0 = w * 16 + (lane >> 4) * 4;
    #pragma unroll
    for (int ct = 0; ct < 10; ++ct)
        #pragma unroll
        for (int r = 0; r < 4; ++r)
            stg[lr0 + r][ct * 16 + (lane & 15)] = (__bf16)fmaxf(acc[ct][r] + gb, 0.f);

    // wave-private coalesced copy: 16 rows x 320 B -> g2 (full lines)
    #pragma unroll
    for (int it = 0; it < 5; ++it) {
        int chunk = it * 64 + lane;            // 0..319
        int lr = chunk / 20, c8 = chunk - lr * 20;
        u16x8 v = *(const u16x8*)&stg[w * 16 + lr][c8 * 8];
        *(u16x8*)(g2 + (size_t)(R0 + lr) * GW + ctg * COLB + c8 * 8) = v;
    }
}

// ---------------------------------------------------------------------------
// W: permute+convert w1 -> w1p[j][t*320 + c] bf16 (c=(n*16+o); pad cols 0)
// ---------------------------------------------------------------------------
__global__ __launch_bounds__(256) void w1_permute(
    const float* __restrict__ w1, __bf16* __restrict__ w1p)
{
    int i = blockIdx.x * 256 + threadIdx.x;    // chunk: j*5120 + t*40 + c8
    if (i >= HID * (KW / 8)) return;
    int j = i / 5120, rem = i - j * 5120;
    int t = rem / 40, c8 = rem - t * 40;
    bf16x8 r;
    if (c8 < 38) {
        int n = c8 >> 1, o0 = (c8 & 1) * 8;
        const float* src = w1 + (size_t)j * KFLAT + n * 2048 + t * 16 + o0;
        #pragma unroll
        for (int e = 0; e < 8; ++e) r[e] = (__bf16)src[e];
    } else {
        #pragma unroll
        for (int e = 0; e < 8; ++e) r[e] = (__bf16)0.f;
    }
    *(bf16x8*)(w1p + (size_t)i * 8) = r;
}

// ---------------------------------------------------------------------------
// G: split-K bf16 MFMA GEMM: partial[kt][b][j] = sum_k g2[b][k]*w1p[j][k]
//    K=40960 over permuted layout; grid (8 m-tiles, 40 k-tiles).
// ---------------------------------------------------------------------------
__global__ __launch_bounds__(256) void gemm_fc1(
    const __bf16* __restrict__ gmat,   // [NB][KW] (g2 viewed flat per b)
    const __bf16* __restrict__ wmat,   // [HID][KW]
    float* __restrict__ partial)       // [NKT][NB][HID]
{
    __shared__ __align__(16) __bf16 At[128][40];
    __shared__ __align__(16) __bf16 Bt[128][40];

    const int tid = threadIdx.x;
    const int b0 = blockIdx.x * 128;
    const int k0 = blockIdx.y * KTILE;

    const int lane = tid & 63;
    const int w = tid >> 6;
    const int wm = (w >> 1) * 64;
    const int wn = (w & 1) * 64;

    const int srow = tid >> 2;
    const int soct = tid & 3;

    f32x4 acc[4][4];
    #pragma unroll
    for (int m = 0; m < 4; ++m)
        #pragma unroll
        for (int n = 0; n < 4; ++n) acc[m][n] = (f32x4){0.f, 0.f, 0.f, 0.f};

    const int arow = lane & 15;
    const int aoct = (lane >> 4) * 8;

    for (int ks = 0; ks < KTILE / 32; ++ks) {
        const int gk = k0 + ks * 32 + soct * 8;
        *(u16x8*)&At[srow     ][soct * 8] = *(const u16x8*)(gmat + (size_t)(b0 + srow     ) * KW + gk);
        *(u16x8*)&At[srow + 64][soct * 8] = *(const u16x8*)(gmat + (size_t)(b0 + srow + 64) * KW + gk);
        *(u16x8*)&Bt[srow     ][soct * 8] = *(const u16x8*)(wmat + (size_t)(srow     ) * KW + gk);
        *(u16x8*)&Bt[srow + 64][soct * 8] = *(const u16x8*)(wmat + (size_t)(srow + 64) * KW + gk);
        __syncthreads();

        bf16x8 af[4], bfr[4];
        #pragma unroll
        for (int m = 0; m < 4; ++m) af[m]  = *(const bf16x8*)&At[wm + m * 16 + arow][aoct];
        #pragma unroll
        for (int n = 0; n < 4; ++n) bfr[n] = *(const bf16x8*)&Bt[wn + n * 16 + arow][aoct];
        #pragma unroll
        for (int m = 0; m < 4; ++m)
            #pragma unroll
            for (int n = 0; n < 4; ++n)
                acc[m][n] = __builtin_amdgcn_mfma_f32_16x16x32_bf16(af[m], bfr[n], acc[m][n], 0, 0, 0);
        __syncthreads();
    }

    float* pout = partial + (size_t)blockIdx.y * (NB * HID);
    #pragma unroll
    for (int m = 0; m < 4; ++m) {
        const int rbase = b0 + wm + m * 16 + (lane >> 4) * 4;
        #pragma unroll
        for (int n = 0; n < 4; ++n) {
            const int col = wn + n * 16 + (lane & 15);
            #pragma unroll
            for (int r = 0; r < 4; ++r)
                pout[(size_t)(rbase + r) * HID + col] = acc[m][n][r];
        }
    }
}

// ---------------------------------------------------------------------------
// R: reduce split-K partials + b1 + ReLU, then FC2 (128->2) + b2
// ---------------------------------------------------------------------------
__global__ __launch_bounds__(128) void reduce_fc2(
    const float* __restrict__ partial,  // [NKT][NB][HID]
    const float* __restrict__ b1,
    const float* __restrict__ w2,       // [NCLS][HID]
    const float* __restrict__ b2,
    float* __restrict__ out)            // [NB][NCLS]
{
    __shared__ float red0[128], red1[128];
    const int b = blockIdx.x, j = threadIdx.x;
    float s = b1[j];
    #pragma unroll 4
    for (int p = 0; p < NKT; ++p) s += partial[(size_t)p * (NB * HID) + b * HID + j];
    float h = fmaxf(s, 0.f);
    red0[j] = h * w2[j];
    red1[j] = h * w2[HID + j];
    __syncthreads();
    for (int off = 64; off > 0; off >>= 1) {
        if (j < off) { red0[j] += red0[j + off]; red1[j] += red1[j + off]; }
        __syncthreads();
    }
    if (j == 0) {
        out[b * 2 + 0] = red0[0] + b2[0];
        out[b * 2 + 1] = red1[0] + b2[1];
    }
}

// ---------------------------------------------------------------------------
extern "C" void kernel_launch(void* const* d_in, const int* in_sizes, int n_in,
                              void* d_out, int out_size, void* d_ws, size_t ws_size,
                              hipStream_t stream) {
    const float* x        = (const float*)d_in[0];
    const float* conv_w   = (const float*)d_in[1];
    const float* conv_b   = (const float*)d_in[2];
    const float* bn_gamma = (const float*)d_in[3];
    const float* bn_beta  = (const float*)d_in[4];
    const float* bn_mean  = (const float*)d_in[5];
    const float* bn_var   = (const float*)d_in[6];
    const float* adj      = (const float*)d_in[7];
    const float* gcn_w    = (const float*)d_in[8];
    const float* gcn_b    = (const float*)d_in[9];
    const float* w1       = (const float*)d_in[10];
    const float* b1       = (const float*)d_in[11];
    const float* w2       = (const float*)d_in[12];
    const float* b2       = (const float*)d_in[13];
    float* out = (float*)d_out;

    // workspace (lifetime-overlapped, ~125.9 MB):
    //   g2   [0,           83,886,080)   mix_gcn -> gemm_fc1
    //   H    [83,886,080, 125,829,120)   conv_pool -> mix_gcn, then DEAD:
    //     w1p  [83,886,080, 94,371,840)  w1_permute (after mix_gcn) -> gemm
    //     part [94,371,840, 115,343,360) gemm -> reduce
    //   m2g  [125,829,120, 125,931,520)  prep_m2 -> mix_gcn
    //   A_g/bnS/bnB small after that
    char* ws = (char*)d_ws;
    __bf16* g2   = (__bf16*)ws;
    __bf16* Hbuf = (__bf16*)(ws + 83886080);
    __bf16* w1p  = (__bf16*)(ws + 83886080);
    float*  part = (float*)(ws + 94371840);
    __bf16* m2g  = (__bf16*)(ws + 125829120);
    float*  A_g  = (float*)(ws + 125931520);
    float*  bnS  = (float*)(ws + 125933568);
    float*  bnB  = (float*)(ws + 125934592);

    prep_small<<<dim3(1), dim3(256), 0, stream>>>(
        adj, bn_gamma, bn_beta, bn_mean, bn_var, conv_b, A_g, bnS, bnB);
    prep_m2<<<dim3(200), dim3(256), 0, stream>>>(A_g, gcn_w, m2g);
    conv_pool<<<dim3(NB * NN), dim3(128), 0, stream>>>(x, conv_w, bnS, bnB, Hbuf);
    mix_gcn<<<dim3((NROWS / 64) * 2), dim3(256), 0, stream>>>(Hbuf, m2g, gcn_b, g2);
    w1_permute<<<dim3(HID * (KW / 8) / 256), dim3(256), 0, stream>>>(w1, w1p);
    gemm_fc1<<<dim3(8, NKT), dim3(256), 0, stream>>>(g2, w1p, part);
    reduce_fc2<<<dim3(NB), dim3(128), 0, stream>>>(part, b1, w2, b2, out);
}

// Round 7
// 132.598 us; speedup vs baseline: 2.2700x; 1.0428x over previous
//
#include <hip/hip_runtime.h>

// ---------------- problem constants ----------------
#define NB    1024
#define NN    19
#define NF    8
#define CCH   152         // NN*NF
#define TLEN  512
#define TP    128
#define GO    16
#define KFLAT 38912       // reference flat K (n*2048 + t*16 + o)
#define HID   128
#define NCLS  2
#define NROWS (NB*TP)     // 131072 (b,t) rows
#define KC    152         // conv channels (j,f)
#define KP    160         // padded K for mix (5*32)
#define NJP   20          // H2 j-planes (19 + zero pad)
#define NOUT  304         // NN*GO
#define COLB  160         // g2 cols per ct-group block
#define GW    320         // g2 padded row width
#define KW    (TP*GW)     // 40960: FC1 K in permuted order
#define M2W   168         // LDS row stride (bank-safe, 16B-aligned)

// FC1 GEMM split-K
#define KTILE 1024
#define NKT   (KW / KTILE)   // 40

typedef float  f32x4  __attribute__((ext_vector_type(4)));
typedef __bf16 bf16x8 __attribute__((ext_vector_type(8)));
typedef __bf16 bf16x4 __attribute__((ext_vector_type(4)));
typedef unsigned short u16x8 __attribute__((ext_vector_type(8)));

// ---------------------------------------------------------------------------
// P1: softmax(adj) + fused BN affine (1 block)
// ---------------------------------------------------------------------------
__global__ __launch_bounds__(256) void prep_small(
    const float* __restrict__ adj,
    const float* __restrict__ bn_gamma, const float* __restrict__ bn_beta,
    const float* __restrict__ bn_mean,  const float* __restrict__ bn_var,
    const float* __restrict__ conv_b,
    float* __restrict__ A_g, float* __restrict__ bnS, float* __restrict__ bnB)
{
    const int tid = threadIdx.x;
    if (tid < NN) {
        float v[NN];
        float m = -1e30f;
        #pragma unroll
        for (int j = 0; j < NN; ++j) { v[j] = adj[tid * NN + j]; m = fmaxf(m, v[j]); }
        float s = 0.f;
        #pragma unroll
        for (int j = 0; j < NN; ++j) { v[j] = expf(v[j] - m); s += v[j]; }
        float rc = 1.f / s;
        #pragma unroll
        for (int j = 0; j < NN; ++j) A_g[tid * NN + j] = v[j] * rc;
    }
    if (tid >= 64 && tid < 64 + CCH) {
        int c = tid - 64;
        float inv = bn_gamma[c] * rsqrtf(bn_var[c] + 1e-5f);
        bnS[c] = inv;
        bnB[c] = conv_b[c] * inv + bn_beta[c] - bn_mean[c] * inv;
    }
}

// ---------------------------------------------------------------------------
// P2: Kronecker matrix m2g[c][k] = A[n,j]*gcn_w[o,f], c=(n*16+o) in [0,320)
//     (rows 304..319 and k 152..159 zero-padded), bf16.
// ---------------------------------------------------------------------------
__global__ __launch_bounds__(256) void prep_m2(
    const float* __restrict__ A_g, const float* __restrict__ gcn_w,
    __bf16* __restrict__ m2g)
{
    int i = blockIdx.x * 256 + threadIdx.x;
    if (i >= GW * KP) return;
    int c = i / KP, k = i - c * KP;
    float v = 0.f;
    if (c < NOUT && k < KC) {
        int n = c >> 4, o = c & 15;
        int j = k >> 3, f = k & 7;
        v = A_g[n * NN + j] * gcn_w[o * NF + f];
    }
    m2g[i] = (__bf16)v;
}

// ---------------------------------------------------------------------------
// A: conv(k5 depthwise)+bias+BN+ReLU+maxpool4 -> H2[j][row][8] bf16.
//    block=(b,n): weights wave-uniform; thread=tp. Consecutive lanes write
//    consecutive 16B -> 2048 B contiguous per wave (fixes R6's 2x write
//    inflation from 320B-strided 16B stores).
// ---------------------------------------------------------------------------
__global__ __launch_bounds__(128) void conv_pool(
    const float* __restrict__ x,       // [NB][NN][TLEN]
    const float* __restrict__ conv_w,  // [CCH][5]
    const float* __restrict__ bnS, const float* __restrict__ bnB,
    __bf16* __restrict__ H)            // [NJP][NROWS][8]
{
    const int bid = blockIdx.x;
    const int b = bid / NN, n = bid - b * NN;
    const int tp = threadIdx.x;

    const float* xr = x + ((size_t)b * NN + n) * TLEN;
    float xv[8];
    #pragma unroll
    for (int e = 0; e < 8; ++e) {
        int tg = 4 * tp - 2 + e;
        xv[e] = (tg >= 0 && tg < TLEN) ? xr[tg] : 0.f;
    }
    const float* cw = conv_w + n * (NF * 5);
    const float* Sp = bnS + n * NF;
    const float* Bp = bnB + n * NF;

    union { __bf16 h[8]; u16x8 v; } hv;
    #pragma unroll
    for (int f = 0; f < NF; ++f) {
        float w0 = cw[f*5+0], w1 = cw[f*5+1], w2 = cw[f*5+2], w3 = cw[f*5+3], w4 = cw[f*5+4];
        float s = Sp[f], bb = Bp[f];
        float m = -1e30f;
        #pragma unroll
        for (int p = 0; p < 4; ++p) {
            float a = xv[p]*w0 + xv[p+1]*w1 + xv[p+2]*w2 + xv[p+3]*w3 + xv[p+4]*w4;
            m = fmaxf(m, a * s + bb);
        }
        hv.h[f] = (__bf16)fmaxf(m, 0.f);
    }
    size_t row = (size_t)b * TP + tp;
    *(u16x8*)(H + ((size_t)n * NROWS + row) * 8) = hv.v;
    if (n == NN - 1) {                         // zero plane j=19 (K pad)
        u16x8 z = {0,0,0,0,0,0,0,0};
        *(u16x8*)(H + ((size_t)(NJP - 1) * NROWS + row) * 8) = z;
    }
}

// ---------------------------------------------------------------------------
// B: MFMA contraction g2 = relu(H @ m2^T + gcn_b), g2[(b,t)][320].
//    A-fragment for k=ks*32+aoct lives at H2[ks*4+(lane>>4)][R0+arow][0..8).
// ---------------------------------------------------------------------------
__global__ __launch_bounds__(256) void mix_gcn(
    const __bf16* __restrict__ H,      // [NJP][NROWS][8]
    const __bf16* __restrict__ m2g,    // [GW][KP]
    const float* __restrict__ gcn_b,   // [GO]
    __bf16* __restrict__ g2)           // [NROWS][GW]
{
    __shared__ __align__(16) __bf16 m2s[COLB][M2W];   // 53,760 B
    __shared__ __align__(16) __bf16 stg[64][M2W];     // 21,504 B
    __shared__ float gbs[GO];

    const int tid = threadIdx.x;
    const int rg  = blockIdx.x >> 1;      // 64-row group
    const int ctg = blockIdx.x & 1;       // ct half (cols ctg*160..+160)

    for (int i = tid; i < COLB * (KP / 8); i += 256) {  // 3200 16B chunks
        int r = i / 20, c8 = i - r * 20;
        *(u16x8*)&m2s[r][c8 * 8] =
            *(const u16x8*)(m2g + (size_t)(ctg * COLB + r) * KP + c8 * 8);
    }
    if (tid < GO) gbs[tid] = gcn_b[tid];
    __syncthreads();

    const int lane = tid & 63, w = tid >> 6;
    const int arow = lane & 15, aoct = (lane >> 4) * 8;
    const int jg = lane >> 4;             // 0..3
    const float gb = gbs[lane & 15];
    const int R0 = rg * 64 + w * 16;

    const __bf16* hp = H + (size_t)(R0 + arow) * 8;
    bf16x8 af[5];
    #pragma unroll
    for (int ks = 0; ks < 5; ++ks)
        af[ks] = *(const bf16x8*)(hp + (size_t)(ks * 4 + jg) * NROWS * 8);

    f32x4 acc[10];
    #pragma unroll
    for (int ct = 0; ct < 10; ++ct) acc[ct] = (f32x4){0.f, 0.f, 0.f, 0.f};

    #pragma unroll
    for (int ks = 0; ks < 5; ++ks)
        #pragma unroll
        for (int ct = 0; ct < 10; ++ct) {
            bf16x8 bfr = *(const bf16x8*)&m2s[ct * 16 + arow][ks * 32 + aoct];
            acc[ct] = __builtin_amdgcn_mfma_f32_16x16x32_bf16(af[ks], bfr, acc[ct], 0, 0, 0);
        }

    // epilogue: acc -> wave-private staging rows [w*16, w*16+16)
    const int lr0 = w * 16 + (lane >> 4) * 4;
    #pragma unroll
    for (int ct = 0; ct < 10; ++ct)
        #pragma unroll
        for (int r = 0; r < 4; ++r)
            stg[lr0 + r][ct * 16 + (lane & 15)] = (__bf16)fmaxf(acc[ct][r] + gb, 0.f);

    // wave-private coalesced copy: 16 rows x 320 B -> g2 (full lines)
    #pragma unroll
    for (int it = 0; it < 5; ++it) {
        int chunk = it * 64 + lane;            // 0..319
        int lr = chunk / 20, c8 = chunk - lr * 20;
        u16x8 v = *(const u16x8*)&stg[w * 16 + lr][c8 * 8];
        *(u16x8*)(g2 + (size_t)(R0 + lr) * GW + ctg * COLB + c8 * 8) = v;
    }
}

// ---------------------------------------------------------------------------
// W: permute+convert w1 -> w1p[j][t*320 + c] bf16 (c=(n*16+o); pad cols 0)
// ---------------------------------------------------------------------------
__global__ __launch_bounds__(256) void w1_permute(
    const float* __restrict__ w1, __bf16* __restrict__ w1p)
{
    int i = blockIdx.x * 256 + threadIdx.x;    // chunk: j*5120 + t*40 + c8
    if (i >= HID * (KW / 8)) return;
    int j = i / 5120, rem = i - j * 5120;
    int t = rem / 40, c8 = rem - t * 40;
    bf16x8 r;
    if (c8 < 38) {
        int n = c8 >> 1, o0 = (c8 & 1) * 8;
        const float* src = w1 + (size_t)j * KFLAT + n * 2048 + t * 16 + o0;
        #pragma unroll
        for (int e = 0; e < 8; ++e) r[e] = (__bf16)src[e];
    } else {
        #pragma unroll
        for (int e = 0; e < 8; ++e) r[e] = (__bf16)0.f;
    }
    *(bf16x8*)(w1p + (size_t)i * 8) = r;
}

// ---------------------------------------------------------------------------
// G: split-K bf16 MFMA GEMM: partial[kt][b][j] = sum_k g2[b][k]*w1p[j][k]
// ---------------------------------------------------------------------------
__global__ __launch_bounds__(256) void gemm_fc1(
    const __bf16* __restrict__ gmat,   // [NB][KW]
    const __bf16* __restrict__ wmat,   // [HID][KW]
    float* __restrict__ partial)       // [NKT][NB][HID]
{
    __shared__ __align__(16) __bf16 At[128][40];
    __shared__ __align__(16) __bf16 Bt[128][40];

    const int tid = threadIdx.x;
    const int b0 = blockIdx.x * 128;
    const int k0 = blockIdx.y * KTILE;

    const int lane = tid & 63;
    const int w = tid >> 6;
    const int wm = (w >> 1) * 64;
    const int wn = (w & 1) * 64;

    const int srow = tid >> 2;
    const int soct = tid & 3;

    f32x4 acc[4][4];
    #pragma unroll
    for (int m = 0; m < 4; ++m)
        #pragma unroll
        for (int n = 0; n < 4; ++n) acc[m][n] = (f32x4){0.f, 0.f, 0.f, 0.f};

    const int arow = lane & 15;
    const int aoct = (lane >> 4) * 8;

    for (int ks = 0; ks < KTILE / 32; ++ks) {
        const int gk = k0 + ks * 32 + soct * 8;
        *(u16x8*)&At[srow     ][soct * 8] = *(const u16x8*)(gmat + (size_t)(b0 + srow     ) * KW + gk);
        *(u16x8*)&At[srow + 64][soct * 8] = *(const u16x8*)(gmat + (size_t)(b0 + srow + 64) * KW + gk);
        *(u16x8*)&Bt[srow     ][soct * 8] = *(const u16x8*)(wmat + (size_t)(srow     ) * KW + gk);
        *(u16x8*)&Bt[srow + 64][soct * 8] = *(const u16x8*)(wmat + (size_t)(srow + 64) * KW + gk);
        __syncthreads();

        bf16x8 af[4], bfr[4];
        #pragma unroll
        for (int m = 0; m < 4; ++m) af[m]  = *(const bf16x8*)&At[wm + m * 16 + arow][aoct];
        #pragma unroll
        for (int n = 0; n < 4; ++n) bfr[n] = *(const bf16x8*)&Bt[wn + n * 16 + arow][aoct];
        #pragma unroll
        for (int m = 0; m < 4; ++m)
            #pragma unroll
            for (int n = 0; n < 4; ++n)
                acc[m][n] = __builtin_amdgcn_mfma_f32_16x16x32_bf16(af[m], bfr[n], acc[m][n], 0, 0, 0);
        __syncthreads();
    }

    float* pout = partial + (size_t)blockIdx.y * (NB * HID);
    #pragma unroll
    for (int m = 0; m < 4; ++m) {
        const int rbase = b0 + wm + m * 16 + (lane >> 4) * 4;
        #pragma unroll
        for (int n = 0; n < 4; ++n) {
            const int col = wn + n * 16 + (lane & 15);
            #pragma unroll
            for (int r = 0; r < 4; ++r)
                pout[(size_t)(rbase + r) * HID + col] = acc[m][n][r];
        }
    }
}

// ---------------------------------------------------------------------------
// R: reduce split-K partials + b1 + ReLU, then FC2 (128->2) + b2
// ---------------------------------------------------------------------------
__global__ __launch_bounds__(128) void reduce_fc2(
    const float* __restrict__ partial,  // [NKT][NB][HID]
    const float* __restrict__ b1,
    const float* __restrict__ w2,       // [NCLS][HID]
    const float* __restrict__ b2,
    float* __restrict__ out)            // [NB][NCLS]
{
    __shared__ float red0[128], red1[128];
    const int b = blockIdx.x, j = threadIdx.x;
    float s = b1[j];
    #pragma unroll 4
    for (int p = 0; p < NKT; ++p) s += partial[(size_t)p * (NB * HID) + b * HID + j];
    float h = fmaxf(s, 0.f);
    red0[j] = h * w2[j];
    red1[j] = h * w2[HID + j];
    __syncthreads();
    for (int off = 64; off > 0; off >>= 1) {
        if (j < off) { red0[j] += red0[j + off]; red1[j] += red1[j + off]; }
        __syncthreads();
    }
    if (j == 0) {
        out[b * 2 + 0] = red0[0] + b2[0];
        out[b * 2 + 1] = red1[0] + b2[1];
    }
}

// ---------------------------------------------------------------------------
extern "C" void kernel_launch(void* const* d_in, const int* in_sizes, int n_in,
                              void* d_out, int out_size, void* d_ws, size_t ws_size,
                              hipStream_t stream) {
    const float* x        = (const float*)d_in[0];
    const float* conv_w   = (const float*)d_in[1];
    const float* conv_b   = (const float*)d_in[2];
    const float* bn_gamma = (const float*)d_in[3];
    const float* bn_beta  = (const float*)d_in[4];
    const float* bn_mean  = (const float*)d_in[5];
    const float* bn_var   = (const float*)d_in[6];
    const float* adj      = (const float*)d_in[7];
    const float* gcn_w    = (const float*)d_in[8];
    const float* gcn_b    = (const float*)d_in[9];
    const float* w1       = (const float*)d_in[10];
    const float* b1       = (const float*)d_in[11];
    const float* w2       = (const float*)d_in[12];
    const float* b2       = (const float*)d_in[13];
    float* out = (float*)d_out;

    // workspace (lifetime-overlapped, ~125.9 MB):
    //   g2   [0,           83,886,080)   mix_gcn -> gemm_fc1
    //   H2   [83,886,080, 125,829,120)   conv_pool -> mix_gcn (20 planes), then DEAD:
    //     w1p  [83,886,080, 94,371,840)  w1_permute (after mix_gcn) -> gemm
    //     part [94,371,840, 115,343,360) gemm -> reduce
    //   m2g  [125,829,120, 125,931,520)  prep_m2 -> mix_gcn
    //   A_g/bnS/bnB small after that
    char* ws = (char*)d_ws;
    __bf16* g2   = (__bf16*)ws;
    __bf16* Hbuf = (__bf16*)(ws + 83886080);
    __bf16* w1p  = (__bf16*)(ws + 83886080);
    float*  part = (float*)(ws + 94371840);
    __bf16* m2g  = (__bf16*)(ws + 125829120);
    float*  A_g  = (float*)(ws + 125931520);
    float*  bnS  = (float*)(ws + 125933568);
    float*  bnB  = (float*)(ws + 125934592);

    prep_small<<<dim3(1), dim3(256), 0, stream>>>(
        adj, bn_gamma, bn_beta, bn_mean, bn_var, conv_b, A_g, bnS, bnB);
    prep_m2<<<dim3(200), dim3(256), 0, stream>>>(A_g, gcn_w, m2g);
    conv_pool<<<dim3(NB * NN), dim3(128), 0, stream>>>(x, conv_w, bnS, bnB, Hbuf);
    mix_gcn<<<dim3((NROWS / 64) * 2), dim3(256), 0, stream>>>(Hbuf, m2g, gcn_b, g2);
    w1_permute<<<dim3(HID * (KW / 8) / 256), dim3(256), 0, stream>>>(w1, w1p);
    gemm_fc1<<<dim3(8, NKT), dim3(256), 0, stream>>>(g2, w1p, part);
    reduce_fc2<<<dim3(NB), dim3(128), 0, stream>>>(part, b1, w2, b2, out);
}

// Round 8
// 132.448 us; speedup vs baseline: 2.2726x; 1.0011x over previous
//
#include <hip/hip_runtime.h>

// ---------------- problem constants ----------------
#define NB    1024
#define NN    19
#define NF    8
#define CCH   152         // NN*NF
#define TLEN  512
#define TP    128
#define GO    16
#define KFLAT 38912       // reference flat K (n*2048 + t*16 + o)
#define HID   128
#define NCLS  2
#define NROWS (NB*TP)     // 131072 (b,t) rows
#define KC    152         // conv channels (j,f)
#define KP    160         // padded K for mix (5*32)
#define NJP   20          // H2 j-planes (19 + zero pad)
#define NOUT  304         // NN*GO
#define COLB  160         // g2 cols per ct-group block
#define GW    320         // g2 padded row width
#define KW    (TP*GW)     // 40960: FC1 K in permuted order
#define M2W   168         // LDS row stride (bank-safe, 16B-aligned)

// FC1 GEMM split-K
#define KTILE 1024
#define NKT   (KW / KTILE)   // 40

typedef float  f32x4  __attribute__((ext_vector_type(4)));
typedef __bf16 bf16x8 __attribute__((ext_vector_type(8)));
typedef __bf16 bf16x4 __attribute__((ext_vector_type(4)));
typedef unsigned short u16x8 __attribute__((ext_vector_type(8)));

// ---------------------------------------------------------------------------
// P1: softmax(adj) + fused BN affine (1 block)
// ---------------------------------------------------------------------------
__global__ __launch_bounds__(256) void prep_small(
    const float* __restrict__ adj,
    const float* __restrict__ bn_gamma, const float* __restrict__ bn_beta,
    const float* __restrict__ bn_mean,  const float* __restrict__ bn_var,
    const float* __restrict__ conv_b,
    float* __restrict__ A_g, float* __restrict__ bnS, float* __restrict__ bnB)
{
    const int tid = threadIdx.x;
    if (tid < NN) {
        float v[NN];
        float m = -1e30f;
        #pragma unroll
        for (int j = 0; j < NN; ++j) { v[j] = adj[tid * NN + j]; m = fmaxf(m, v[j]); }
        float s = 0.f;
        #pragma unroll
        for (int j = 0; j < NN; ++j) { v[j] = expf(v[j] - m); s += v[j]; }
        float rc = 1.f / s;
        #pragma unroll
        for (int j = 0; j < NN; ++j) A_g[tid * NN + j] = v[j] * rc;
    }
    if (tid >= 64 && tid < 64 + CCH) {
        int c = tid - 64;
        float inv = bn_gamma[c] * rsqrtf(bn_var[c] + 1e-5f);
        bnS[c] = inv;
        bnB[c] = conv_b[c] * inv + bn_beta[c] - bn_mean[c] * inv;
    }
}

// ---------------------------------------------------------------------------
// P2: Kronecker matrix m2g[c][k] = A[n,j]*gcn_w[o,f], c=(n*16+o) in [0,320)
// ---------------------------------------------------------------------------
__global__ __launch_bounds__(256) void prep_m2(
    const float* __restrict__ A_g, const float* __restrict__ gcn_w,
    __bf16* __restrict__ m2g)
{
    int i = blockIdx.x * 256 + threadIdx.x;
    if (i >= GW * KP) return;
    int c = i / KP, k = i - c * KP;
    float v = 0.f;
    if (c < NOUT && k < KC) {
        int n = c >> 4, o = c & 15;
        int j = k >> 3, f = k & 7;
        v = A_g[n * NN + j] * gcn_w[o * NF + f];
    }
    m2g[i] = (__bf16)v;
}

// ---------------------------------------------------------------------------
// A: conv(k5 depthwise)+bias+BN+ReLU+maxpool4 -> H2[j][row][8] bf16.
//    block=(b,n): weights wave-uniform; consecutive lanes write consecutive
//    16B (coalesced).
// ---------------------------------------------------------------------------
__global__ __launch_bounds__(128) void conv_pool(
    const float* __restrict__ x,       // [NB][NN][TLEN]
    const float* __restrict__ conv_w,  // [CCH][5]
    const float* __restrict__ bnS, const float* __restrict__ bnB,
    __bf16* __restrict__ H)            // [NJP][NROWS][8]
{
    const int bid = blockIdx.x;
    const int b = bid / NN, n = bid - b * NN;
    const int tp = threadIdx.x;

    const float* xr = x + ((size_t)b * NN + n) * TLEN;
    float xv[8];
    #pragma unroll
    for (int e = 0; e < 8; ++e) {
        int tg = 4 * tp - 2 + e;
        xv[e] = (tg >= 0 && tg < TLEN) ? xr[tg] : 0.f;
    }
    const float* cw = conv_w + n * (NF * 5);
    const float* Sp = bnS + n * NF;
    const float* Bp = bnB + n * NF;

    union { __bf16 h[8]; u16x8 v; } hv;
    #pragma unroll
    for (int f = 0; f < NF; ++f) {
        float w0 = cw[f*5+0], w1 = cw[f*5+1], w2 = cw[f*5+2], w3 = cw[f*5+3], w4 = cw[f*5+4];
        float s = Sp[f], bb = Bp[f];
        float m = -1e30f;
        #pragma unroll
        for (int p = 0; p < 4; ++p) {
            float a = xv[p]*w0 + xv[p+1]*w1 + xv[p+2]*w2 + xv[p+3]*w3 + xv[p+4]*w4;
            m = fmaxf(m, a * s + bb);
        }
        hv.h[f] = (__bf16)fmaxf(m, 0.f);
    }
    size_t row = (size_t)b * TP + tp;
    *(u16x8*)(H + ((size_t)n * NROWS + row) * 8) = hv.v;
    if (n == NN - 1) {                         // zero plane j=19 (K pad)
        u16x8 z = {0,0,0,0,0,0,0,0};
        *(u16x8*)(H + ((size_t)(NJP - 1) * NROWS + row) * 8) = z;
    }
}

// ---------------------------------------------------------------------------
// B: MFMA contraction (C^T form) g2 = relu(H @ m2^T + gcn_b).
//    Operand swap: mfma(m2_frag, H_frag, acc) — identical loads to the
//    direct form (A/B fragment layouts are mutually transposed), but each
//    lane's 4 acc values become 4 CONSECUTIVE g2 columns of one row ->
//    epilogue is 10x ds_write_b64 (bank-balanced) instead of 40x b16
//    (4-way conflicted: R7's 3.9M conflict cycles).
// ---------------------------------------------------------------------------
__global__ __launch_bounds__(256) void mix_gcn(
    const __bf16* __restrict__ H,      // [NJP][NROWS][8]
    const __bf16* __restrict__ m2g,    // [GW][KP]
    const float* __restrict__ gcn_b,   // [GO]
    __bf16* __restrict__ g2)           // [NROWS][GW]
{
    __shared__ __align__(16) __bf16 m2s[COLB][M2W];   // 53,760 B
    __shared__ __align__(16) __bf16 stg[64][M2W];     // 21,504 B
    __shared__ float gbs[GO];

    const int tid = threadIdx.x;
    const int rg  = blockIdx.x >> 1;      // 64-row group
    const int ctg = blockIdx.x & 1;       // ct half (cols ctg*160..+160)

    for (int i = tid; i < COLB * (KP / 8); i += 256) {  // 3200 16B chunks
        int r = i / 20, c8 = i - r * 20;
        *(u16x8*)&m2s[r][c8 * 8] =
            *(const u16x8*)(m2g + (size_t)(ctg * COLB + r) * KP + c8 * 8);
    }
    if (tid < GO) gbs[tid] = gcn_b[tid];
    __syncthreads();

    const int lane = tid & 63, w = tid >> 6;
    const int arow = lane & 15, aoct = (lane >> 4) * 8;
    const int jg = lane >> 4;             // 0..3
    const int R0 = rg * 64 + w * 16;

    // H fragments (B-operand in C^T form): lane supplies col = R0+arow,
    // k-octet = ks*32 + jg*8  ->  plane ks*4+jg, row R0+arow.
    const __bf16* hp = H + (size_t)(R0 + arow) * 8;
    bf16x8 af[5];
    #pragma unroll
    for (int ks = 0; ks < 5; ++ks)
        af[ks] = *(const bf16x8*)(hp + (size_t)(ks * 4 + jg) * NROWS * 8);

    f32x4 acc[10];
    #pragma unroll
    for (int ct = 0; ct < 10; ++ct) acc[ct] = (f32x4){0.f, 0.f, 0.f, 0.f};

    #pragma unroll
    for (int ks = 0; ks < 5; ++ks)
        #pragma unroll
        for (int ct = 0; ct < 10; ++ct) {
            // m2 fragment (A-operand): row ct*16+arow, k-octet ks*32+jg*8
            bf16x8 bfr = *(const bf16x8*)&m2s[ct * 16 + arow][ks * 32 + aoct];
            acc[ct] = __builtin_amdgcn_mfma_f32_16x16x32_bf16(bfr, af[ks], acc[ct], 0, 0, 0);
        }

    // epilogue (C^T): lane holds c = ct*16 + jg*4 + r for g2 row R0+(lane&15)
    const int growl = w * 16 + (lane & 15);
    const float gb0 = gbs[jg * 4 + 0], gb1 = gbs[jg * 4 + 1];
    const float gb2 = gbs[jg * 4 + 2], gb3 = gbs[jg * 4 + 3];
    #pragma unroll
    for (int ct = 0; ct < 10; ++ct) {
        bf16x4 v;
        v[0] = (__bf16)fmaxf(acc[ct][0] + gb0, 0.f);
        v[1] = (__bf16)fmaxf(acc[ct][1] + gb1, 0.f);
        v[2] = (__bf16)fmaxf(acc[ct][2] + gb2, 0.f);
        v[3] = (__bf16)fmaxf(acc[ct][3] + gb3, 0.f);
        *(bf16x4*)&stg[growl][ct * 16 + jg * 4] = v;
    }

    // wave-private coalesced copy: 16 rows x 320 B -> g2 (full lines)
    #pragma unroll
    for (int it = 0; it < 5; ++it) {
        int chunk = it * 64 + lane;            // 0..319
        int lr = chunk / 20, c8 = chunk - lr * 20;
        u16x8 v = *(const u16x8*)&stg[w * 16 + lr][c8 * 8];
        *(u16x8*)(g2 + (size_t)(R0 + lr) * GW + ctg * COLB + c8 * 8) = v;
    }
}

// ---------------------------------------------------------------------------
// W: permute+convert w1 -> w1p[j][t*320 + c] bf16 (c=(n*16+o); pad cols 0)
// ---------------------------------------------------------------------------
__global__ __launch_bounds__(256) void w1_permute(
    const float* __restrict__ w1, __bf16* __restrict__ w1p)
{
    int i = blockIdx.x * 256 + threadIdx.x;    // chunk: j*5120 + t*40 + c8
    if (i >= HID * (KW / 8)) return;
    int j = i / 5120, rem = i - j * 5120;
    int t = rem / 40, c8 = rem - t * 40;
    bf16x8 r;
    if (c8 < 38) {
        int n = c8 >> 1, o0 = (c8 & 1) * 8;
        const float* src = w1 + (size_t)j * KFLAT + n * 2048 + t * 16 + o0;
        #pragma unroll
        for (int e = 0; e < 8; ++e) r[e] = (__bf16)src[e];
    } else {
        #pragma unroll
        for (int e = 0; e < 8; ++e) r[e] = (__bf16)0.f;
    }
    *(bf16x8*)(w1p + (size_t)i * 8) = r;
}

// ---------------------------------------------------------------------------
// G: split-K bf16 MFMA GEMM: partial[kt][b][j] = sum_k g2[b][k]*w1p[j][k]
// ---------------------------------------------------------------------------
__global__ __launch_bounds__(256) void gemm_fc1(
    const __bf16* __restrict__ gmat,   // [NB][KW]
    const __bf16* __restrict__ wmat,   // [HID][KW]
    float* __restrict__ partial)       // [NKT][NB][HID]
{
    __shared__ __align__(16) __bf16 At[128][40];
    __shared__ __align__(16) __bf16 Bt[128][40];

    const int tid = threadIdx.x;
    const int b0 = blockIdx.x * 128;
    const int k0 = blockIdx.y * KTILE;

    const int lane = tid & 63;
    const int w = tid >> 6;
    const int wm = (w >> 1) * 64;
    const int wn = (w & 1) * 64;

    const int srow = tid >> 2;
    const int soct = tid & 3;

    f32x4 acc[4][4];
    #pragma unroll
    for (int m = 0; m < 4; ++m)
        #pragma unroll
        for (int n = 0; n < 4; ++n) acc[m][n] = (f32x4){0.f, 0.f, 0.f, 0.f};

    const int arow = lane & 15;
    const int aoct = (lane >> 4) * 8;

    for (int ks = 0; ks < KTILE / 32; ++ks) {
        const int gk = k0 + ks * 32 + soct * 8;
        *(u16x8*)&At[srow     ][soct * 8] = *(const u16x8*)(gmat + (size_t)(b0 + srow     ) * KW + gk);
        *(u16x8*)&At[srow + 64][soct * 8] = *(const u16x8*)(gmat + (size_t)(b0 + srow + 64) * KW + gk);
        *(u16x8*)&Bt[srow     ][soct * 8] = *(const u16x8*)(wmat + (size_t)(srow     ) * KW + gk);
        *(u16x8*)&Bt[srow + 64][soct * 8] = *(const u16x8*)(wmat + (size_t)(srow + 64) * KW + gk);
        __syncthreads();

        bf16x8 af[4], bfr[4];
        #pragma unroll
        for (int m = 0; m < 4; ++m) af[m]  = *(const bf16x8*)&At[wm + m * 16 + arow][aoct];
        #pragma unroll
        for (int n = 0; n < 4; ++n) bfr[n] = *(const bf16x8*)&Bt[wn + n * 16 + arow][aoct];
        #pragma unroll
        for (int m = 0; m < 4; ++m)
            #pragma unroll
            for (int n = 0; n < 4; ++n)
                acc[m][n] = __builtin_amdgcn_mfma_f32_16x16x32_bf16(af[m], bfr[n], acc[m][n], 0, 0, 0);
        __syncthreads();
    }

    float* pout = partial + (size_t)blockIdx.y * (NB * HID);
    #pragma unroll
    for (int m = 0; m < 4; ++m) {
        const int rbase = b0 + wm + m * 16 + (lane >> 4) * 4;
        #pragma unroll
        for (int n = 0; n < 4; ++n) {
            const int col = wn + n * 16 + (lane & 15);
            #pragma unroll
            for (int r = 0; r < 4; ++r)
                pout[(size_t)(rbase + r) * HID + col] = acc[m][n][r];
        }
    }
}

// ---------------------------------------------------------------------------
// R: reduce split-K partials + b1 + ReLU, then FC2 (128->2) + b2
// ---------------------------------------------------------------------------
__global__ __launch_bounds__(128) void reduce_fc2(
    const float* __restrict__ partial,  // [NKT][NB][HID]
    const float* __restrict__ b1,
    const float* __restrict__ w2,       // [NCLS][HID]
    const float* __restrict__ b2,
    float* __restrict__ out)            // [NB][NCLS]
{
    __shared__ float red0[128], red1[128];
    const int b = blockIdx.x, j = threadIdx.x;
    float s = b1[j];
    #pragma unroll 4
    for (int p = 0; p < NKT; ++p) s += partial[(size_t)p * (NB * HID) + b * HID + j];
    float h = fmaxf(s, 0.f);
    red0[j] = h * w2[j];
    red1[j] = h * w2[HID + j];
    __syncthreads();
    for (int off = 64; off > 0; off >>= 1) {
        if (j < off) { red0[j] += red0[j + off]; red1[j] += red1[j + off]; }
        __syncthreads();
    }
    if (j == 0) {
        out[b * 2 + 0] = red0[0] + b2[0];
        out[b * 2 + 1] = red1[0] + b2[1];
    }
}

// ---------------------------------------------------------------------------
extern "C" void kernel_launch(void* const* d_in, const int* in_sizes, int n_in,
                              void* d_out, int out_size, void* d_ws, size_t ws_size,
                              hipStream_t stream) {
    const float* x        = (const float*)d_in[0];
    const float* conv_w   = (const float*)d_in[1];
    const float* conv_b   = (const float*)d_in[2];
    const float* bn_gamma = (const float*)d_in[3];
    const float* bn_beta  = (const float*)d_in[4];
    const float* bn_mean  = (const float*)d_in[5];
    const float* bn_var   = (const float*)d_in[6];
    const float* adj      = (const float*)d_in[7];
    const float* gcn_w    = (const float*)d_in[8];
    const float* gcn_b    = (const float*)d_in[9];
    const float* w1       = (const float*)d_in[10];
    const float* b1       = (const float*)d_in[11];
    const float* w2       = (const float*)d_in[12];
    const float* b2       = (const float*)d_in[13];
    float* out = (float*)d_out;

    // workspace (lifetime-overlapped, ~125.9 MB):
    //   g2   [0,           83,886,080)   mix_gcn -> gemm_fc1
    //   H2   [83,886,080, 125,829,120)   conv_pool -> mix_gcn, then DEAD:
    //     w1p  [83,886,080, 94,371,840)  w1_permute (after mix_gcn) -> gemm
    //     part [94,371,840, 115,343,360) gemm -> reduce
    //   m2g  [125,829,120, 125,931,520)  prep_m2 -> mix_gcn
    //   A_g/bnS/bnB small after that
    char* ws = (char*)d_ws;
    __bf16* g2   = (__bf16*)ws;
    __bf16* Hbuf = (__bf16*)(ws + 83886080);
    __bf16* w1p  = (__bf16*)(ws + 83886080);
    float*  part = (float*)(ws + 94371840);
    __bf16* m2g  = (__bf16*)(ws + 125829120);
    float*  A_g  = (float*)(ws + 125931520);
    float*  bnS  = (float*)(ws + 125933568);
    float*  bnB  = (float*)(ws + 125934592);

    prep_small<<<dim3(1), dim3(256), 0, stream>>>(
        adj, bn_gamma, bn_beta, bn_mean, bn_var, conv_b, A_g, bnS, bnB);
    prep_m2<<<dim3(200), dim3(256), 0, stream>>>(A_g, gcn_w, m2g);
    conv_pool<<<dim3(NB * NN), dim3(128), 0, stream>>>(x, conv_w, bnS, bnB, Hbuf);
    mix_gcn<<<dim3((NROWS / 64) * 2), dim3(256), 0, stream>>>(Hbuf, m2g, gcn_b, g2);
    w1_permute<<<dim3(HID * (KW / 8) / 256), dim3(256), 0, stream>>>(w1, w1p);
    gemm_fc1<<<dim3(8, NKT), dim3(256), 0, stream>>>(g2, w1p, part);
    reduce_fc2<<<dim3(NB), dim3(128), 0, stream>>>(part, b1, w2, b2, out);
}

// Round 9
// 111.589 us; speedup vs baseline: 2.6974x; 1.1869x over previous
//
#include <hip/hip_runtime.h>

// ---------------- problem constants ----------------
#define NB    1024
#define NN    19
#define NF    8
#define CCH   152         // NN*NF
#define TLEN  512
#define TP    128
#define GO    16
#define KFLAT 38912       // reference flat K (n*2048 + t*16 + o)
#define HID   128
#define NCLS  2
#define NROWS (NB*TP)     // 131072 (b,t) rows
#define KC    152         // conv channels (j,f)
#define KP    160         // padded K for mix (5*32)
#define NJP   20          // H2 j-planes (19 + zero pad)
#define NOUT  304         // NN*GO
#define GW    320         // g2 padded row width
#define KW    (TP*GW)     // 40960: FC1 K in permuted order

// FC1 GEMM split-K
#define KTILE 1024
#define NKT   (KW / KTILE)   // 40

typedef float  f32x4  __attribute__((ext_vector_type(4)));
typedef __bf16 bf16x8 __attribute__((ext_vector_type(8)));
typedef __bf16 bf16x4 __attribute__((ext_vector_type(4)));
typedef unsigned short u16x8 __attribute__((ext_vector_type(8)));

// ---------------------------------------------------------------------------
// P1: softmax(adj) + fused BN affine (1 block)
// ---------------------------------------------------------------------------
__global__ __launch_bounds__(256) void prep_small(
    const float* __restrict__ adj,
    const float* __restrict__ bn_gamma, const float* __restrict__ bn_beta,
    const float* __restrict__ bn_mean,  const float* __restrict__ bn_var,
    const float* __restrict__ conv_b,
    float* __restrict__ A_g, float* __restrict__ bnS, float* __restrict__ bnB)
{
    const int tid = threadIdx.x;
    if (tid < NN) {
        float v[NN];
        float m = -1e30f;
        #pragma unroll
        for (int j = 0; j < NN; ++j) { v[j] = adj[tid * NN + j]; m = fmaxf(m, v[j]); }
        float s = 0.f;
        #pragma unroll
        for (int j = 0; j < NN; ++j) { v[j] = expf(v[j] - m); s += v[j]; }
        float rc = 1.f / s;
        #pragma unroll
        for (int j = 0; j < NN; ++j) A_g[tid * NN + j] = v[j] * rc;
    }
    if (tid >= 64 && tid < 64 + CCH) {
        int c = tid - 64;
        float inv = bn_gamma[c] * rsqrtf(bn_var[c] + 1e-5f);
        bnS[c] = inv;
        bnB[c] = conv_b[c] * inv + bn_beta[c] - bn_mean[c] * inv;
    }
}

// ---------------------------------------------------------------------------
// P2: Kronecker matrix m2g[c][k] = A[n,j]*gcn_w[o,f], c=(n*16+o) in [0,320)
// ---------------------------------------------------------------------------
__global__ __launch_bounds__(256) void prep_m2(
    const float* __restrict__ A_g, const float* __restrict__ gcn_w,
    __bf16* __restrict__ m2g)
{
    int i = blockIdx.x * 256 + threadIdx.x;
    if (i >= GW * KP) return;
    int c = i / KP, k = i - c * KP;
    float v = 0.f;
    if (c < NOUT && k < KC) {
        int n = c >> 4, o = c & 15;
        int j = k >> 3, f = k & 7;
        v = A_g[n * NN + j] * gcn_w[o * NF + f];
    }
    m2g[i] = (__bf16)v;
}

// ---------------------------------------------------------------------------
// A: conv(k5 depthwise)+bias+BN+ReLU+maxpool4 -> H2[j][row][8] bf16.
// ---------------------------------------------------------------------------
__global__ __launch_bounds__(128) void conv_pool(
    const float* __restrict__ x,       // [NB][NN][TLEN]
    const float* __restrict__ conv_w,  // [CCH][5]
    const float* __restrict__ bnS, const float* __restrict__ bnB,
    __bf16* __restrict__ H)            // [NJP][NROWS][8]
{
    const int bid = blockIdx.x;
    const int b = bid / NN, n = bid - b * NN;
    const int tp = threadIdx.x;

    const float* xr = x + ((size_t)b * NN + n) * TLEN;
    float xv[8];
    #pragma unroll
    for (int e = 0; e < 8; ++e) {
        int tg = 4 * tp - 2 + e;
        xv[e] = (tg >= 0 && tg < TLEN) ? xr[tg] : 0.f;
    }
    const float* cw = conv_w + n * (NF * 5);
    const float* Sp = bnS + n * NF;
    const float* Bp = bnB + n * NF;

    union { __bf16 h[8]; u16x8 v; } hv;
    #pragma unroll
    for (int f = 0; f < NF; ++f) {
        float w0 = cw[f*5+0], w1 = cw[f*5+1], w2 = cw[f*5+2], w3 = cw[f*5+3], w4 = cw[f*5+4];
        float s = Sp[f], bb = Bp[f];
        float m = -1e30f;
        #pragma unroll
        for (int p = 0; p < 4; ++p) {
            float a = xv[p]*w0 + xv[p+1]*w1 + xv[p+2]*w2 + xv[p+3]*w3 + xv[p+4]*w4;
            m = fmaxf(m, a * s + bb);
        }
        hv.h[f] = (__bf16)fmaxf(m, 0.f);
    }
    size_t row = (size_t)b * TP + tp;
    *(u16x8*)(H + ((size_t)n * NROWS + row) * 8) = hv.v;
    if (n == NN - 1) {                         // zero plane j=19 (K pad)
        u16x8 z = {0,0,0,0,0,0,0,0};
        *(u16x8*)(H + ((size_t)(NJP - 1) * NROWS + row) * 8) = z;
    }
}

// ---------------------------------------------------------------------------
// B: MFMA contraction (C^T form) g2 = relu(H @ m2^T + gcn_b).
//    v2: ZERO LDS, ZERO barriers. Each wave owns 5 ct-tiles (80 cols);
//    its 25 m2 fragments live in VGPRs, loaded ONCE per block from L2.
//    Block = 128 rows x full 320 cols; 8 row-tile iterations.
//    Epilogue: direct bf16x4 stores — per instruction each g2 row gets one
//    full 32B sector (no partial-sector write inflation).
// ---------------------------------------------------------------------------
__global__ __launch_bounds__(256) void mix_gcn(
    const __bf16* __restrict__ H,      // [NJP][NROWS][8]
    const __bf16* __restrict__ m2g,    // [GW][KP]
    const float* __restrict__ gcn_b,   // [GO]
    __bf16* __restrict__ g2)           // [NROWS][GW]
{
    const int tid  = threadIdx.x;
    const int lane = tid & 63, w = tid >> 6;
    const int arow = lane & 15;
    const int jg   = lane >> 4;           // 0..3
    const int ct0  = w * 5;               // wave's first ct-tile (of 20)

    // bias for this lane's 4 output cols: c % 16 = jg*4 + r
    const float4 gbv = *(const float4*)(gcn_b + jg * 4);

    // m2 fragments (A-operand), once per block from L2:
    // frag(ct,ks): row (ct0+ct)*16+arow, elems ks*32 + jg*8 .. +8
    bf16x8 mf[5][5];
    #pragma unroll
    for (int ct = 0; ct < 5; ++ct)
        #pragma unroll
        for (int ks = 0; ks < 5; ++ks)
            mf[ct][ks] = *(const bf16x8*)(
                m2g + (size_t)((ct0 + ct) * 16 + arow) * KP + ks * 32 + jg * 8);

    const int Rbase = blockIdx.x * 128;
    for (int it = 0; it < 8; ++it) {
        const int R0 = Rbase + it * 16;

        // H fragments (B-operand): col = R0+arow, k-octet ks*32+jg*8
        // -> plane ks*4+jg, row R0+arow
        const __bf16* hp = H + (size_t)(R0 + arow) * 8;
        bf16x8 af[5];
        #pragma unroll
        for (int ks = 0; ks < 5; ++ks)
            af[ks] = *(const bf16x8*)(hp + (size_t)(ks * 4 + jg) * NROWS * 8);

        f32x4 acc[5];
        #pragma unroll
        for (int ct = 0; ct < 5; ++ct) acc[ct] = (f32x4){0.f, 0.f, 0.f, 0.f};

        #pragma unroll
        for (int ks = 0; ks < 5; ++ks)
            #pragma unroll
            for (int ct = 0; ct < 5; ++ct)
                acc[ct] = __builtin_amdgcn_mfma_f32_16x16x32_bf16(mf[ct][ks], af[ks], acc[ct], 0, 0, 0);

        // C^T: lane holds cols c = (ct0+ct)*16 + jg*4 + r, row R0+arow
        __bf16* gp = g2 + (size_t)(R0 + arow) * GW + ct0 * 16 + jg * 4;
        #pragma unroll
        for (int ct = 0; ct < 5; ++ct) {
            bf16x4 v;
            v[0] = (__bf16)fmaxf(acc[ct][0] + gbv.x, 0.f);
            v[1] = (__bf16)fmaxf(acc[ct][1] + gbv.y, 0.f);
            v[2] = (__bf16)fmaxf(acc[ct][2] + gbv.z, 0.f);
            v[3] = (__bf16)fmaxf(acc[ct][3] + gbv.w, 0.f);
            *(bf16x4*)(gp + ct * 16) = v;
        }
    }
}

// ---------------------------------------------------------------------------
// W: permute+convert w1 -> w1p[j][t*320 + c] bf16 (c=(n*16+o); pad cols 0)
// ---------------------------------------------------------------------------
__global__ __launch_bounds__(256) void w1_permute(
    const float* __restrict__ w1, __bf16* __restrict__ w1p)
{
    int i = blockIdx.x * 256 + threadIdx.x;    // chunk: j*5120 + t*40 + c8
    if (i >= HID * (KW / 8)) return;
    int j = i / 5120, rem = i - j * 5120;
    int t = rem / 40, c8 = rem - t * 40;
    bf16x8 r;
    if (c8 < 38) {
        int n = c8 >> 1, o0 = (c8 & 1) * 8;
        const float* src = w1 + (size_t)j * KFLAT + n * 2048 + t * 16 + o0;
        #pragma unroll
        for (int e = 0; e < 8; ++e) r[e] = (__bf16)src[e];
    } else {
        #pragma unroll
        for (int e = 0; e < 8; ++e) r[e] = (__bf16)0.f;
    }
    *(bf16x8*)(w1p + (size_t)i * 8) = r;
}

// ---------------------------------------------------------------------------
// G: split-K bf16 MFMA GEMM: partial[kt][b][j] = sum_k g2[b][k]*w1p[j][k]
// ---------------------------------------------------------------------------
__global__ __launch_bounds__(256) void gemm_fc1(
    const __bf16* __restrict__ gmat,   // [NB][KW]
    const __bf16* __restrict__ wmat,   // [HID][KW]
    float* __restrict__ partial)       // [NKT][NB][HID]
{
    __shared__ __align__(16) __bf16 At[128][40];
    __shared__ __align__(16) __bf16 Bt[128][40];

    const int tid = threadIdx.x;
    const int b0 = blockIdx.x * 128;
    const int k0 = blockIdx.y * KTILE;

    const int lane = tid & 63;
    const int w = tid >> 6;
    const int wm = (w >> 1) * 64;
    const int wn = (w & 1) * 64;

    const int srow = tid >> 2;
    const int soct = tid & 3;

    f32x4 acc[4][4];
    #pragma unroll
    for (int m = 0; m < 4; ++m)
        #pragma unroll
        for (int n = 0; n < 4; ++n) acc[m][n] = (f32x4){0.f, 0.f, 0.f, 0.f};

    const int arow = lane & 15;
    const int aoct = (lane >> 4) * 8;

    for (int ks = 0; ks < KTILE / 32; ++ks) {
        const int gk = k0 + ks * 32 + soct * 8;
        *(u16x8*)&At[srow     ][soct * 8] = *(const u16x8*)(gmat + (size_t)(b0 + srow     ) * KW + gk);
        *(u16x8*)&At[srow + 64][soct * 8] = *(const u16x8*)(gmat + (size_t)(b0 + srow + 64) * KW + gk);
        *(u16x8*)&Bt[srow     ][soct * 8] = *(const u16x8*)(wmat + (size_t)(srow     ) * KW + gk);
        *(u16x8*)&Bt[srow + 64][soct * 8] = *(const u16x8*)(wmat + (size_t)(srow + 64) * KW + gk);
        __syncthreads();

        bf16x8 af[4], bfr[4];
        #pragma unroll
        for (int m = 0; m < 4; ++m) af[m]  = *(const bf16x8*)&At[wm + m * 16 + arow][aoct];
        #pragma unroll
        for (int n = 0; n < 4; ++n) bfr[n] = *(const bf16x8*)&Bt[wn + n * 16 + arow][aoct];
        #pragma unroll
        for (int m = 0; m < 4; ++m)
            #pragma unroll
            for (int n = 0; n < 4; ++n)
                acc[m][n] = __builtin_amdgcn_mfma_f32_16x16x32_bf16(af[m], bfr[n], acc[m][n], 0, 0, 0);
        __syncthreads();
    }

    float* pout = partial + (size_t)blockIdx.y * (NB * HID);
    #pragma unroll
    for (int m = 0; m < 4; ++m) {
        const int rbase = b0 + wm + m * 16 + (lane >> 4) * 4;
        #pragma unroll
        for (int n = 0; n < 4; ++n) {
            const int col = wn + n * 16 + (lane & 15);
            #pragma unroll
            for (int r = 0; r < 4; ++r)
                pout[(size_t)(rbase + r) * HID + col] = acc[m][n][r];
        }
    }
}

// ---------------------------------------------------------------------------
// R: reduce split-K partials + b1 + ReLU, then FC2 (128->2) + b2
// ---------------------------------------------------------------------------
__global__ __launch_bounds__(128) void reduce_fc2(
    const float* __restrict__ partial,  // [NKT][NB][HID]
    const float* __restrict__ b1,
    const float* __restrict__ w2,       // [NCLS][HID]
    const float* __restrict__ b2,
    float* __restrict__ out)            // [NB][NCLS]
{
    __shared__ float red0[128], red1[128];
    const int b = blockIdx.x, j = threadIdx.x;
    float s = b1[j];
    #pragma unroll 4
    for (int p = 0; p < NKT; ++p) s += partial[(size_t)p * (NB * HID) + b * HID + j];
    float h = fmaxf(s, 0.f);
    red0[j] = h * w2[j];
    red1[j] = h * w2[HID + j];
    __syncthreads();
    for (int off = 64; off > 0; off >>= 1) {
        if (j < off) { red0[j] += red0[j + off]; red1[j] += red1[j + off]; }
        __syncthreads();
    }
    if (j == 0) {
        out[b * 2 + 0] = red0[0] + b2[0];
        out[b * 2 + 1] = red1[0] + b2[1];
    }
}

// ---------------------------------------------------------------------------
extern "C" void kernel_launch(void* const* d_in, const int* in_sizes, int n_in,
                              void* d_out, int out_size, void* d_ws, size_t ws_size,
                              hipStream_t stream) {
    const float* x        = (const float*)d_in[0];
    const float* conv_w   = (const float*)d_in[1];
    const float* conv_b   = (const float*)d_in[2];
    const float* bn_gamma = (const float*)d_in[3];
    const float* bn_beta  = (const float*)d_in[4];
    const float* bn_mean  = (const float*)d_in[5];
    const float* bn_var   = (const float*)d_in[6];
    const float* adj      = (const float*)d_in[7];
    const float* gcn_w    = (const float*)d_in[8];
    const float* gcn_b    = (const float*)d_in[9];
    const float* w1       = (const float*)d_in[10];
    const float* b1       = (const float*)d_in[11];
    const float* w2       = (const float*)d_in[12];
    const float* b2       = (const float*)d_in[13];
    float* out = (float*)d_out;

    // workspace (lifetime-overlapped, ~125.9 MB):
    //   g2   [0,           83,886,080)   mix_gcn -> gemm_fc1
    //   H2   [83,886,080, 125,829,120)   conv_pool -> mix_gcn, then DEAD:
    //     w1p  [83,886,080, 94,371,840)  w1_permute (after mix_gcn) -> gemm
    //     part [94,371,840, 115,343,360) gemm -> reduce
    //   m2g  [125,829,120, 125,931,520)  prep_m2 -> mix_gcn
    //   A_g/bnS/bnB small after that
    char* ws = (char*)d_ws;
    __bf16* g2   = (__bf16*)ws;
    __bf16* Hbuf = (__bf16*)(ws + 83886080);
    __bf16* w1p  = (__bf16*)(ws + 83886080);
    float*  part = (float*)(ws + 94371840);
    __bf16* m2g  = (__bf16*)(ws + 125829120);
    float*  A_g  = (float*)(ws + 125931520);
    float*  bnS  = (float*)(ws + 125933568);
    float*  bnB  = (float*)(ws + 125934592);

    prep_small<<<dim3(1), dim3(256), 0, stream>>>(
        adj, bn_gamma, bn_beta, bn_mean, bn_var, conv_b, A_g, bnS, bnB);
    prep_m2<<<dim3(200), dim3(256), 0, stream>>>(A_g, gcn_w, m2g);
    conv_pool<<<dim3(NB * NN), dim3(128), 0, stream>>>(x, conv_w, bnS, bnB, Hbuf);
    mix_gcn<<<dim3(NROWS / 128), dim3(256), 0, stream>>>(Hbuf, m2g, gcn_b, g2);
    w1_permute<<<dim3(HID * (KW / 8) / 256), dim3(256), 0, stream>>>(w1, w1p);
    gemm_fc1<<<dim3(8, NKT), dim3(256), 0, stream>>>(g2, w1p, part);
    reduce_fc2<<<dim3(NB), dim3(128), 0, stream>>>(part, b1, w2, b2, out);
}